// Round 9
// baseline (80.619 us; speedup 1.0000x reference)
//
#include <hip/hip_runtime.h>

#define MAXL 33
#define CSTR 36  // u8 count-slice stride (9 dwords, dword-aligned per thread)
#define PB 128   // blocks per batch image
#define TPB 128  // threads per block
#define GSTR (PB * TPB)  // grid stride in float4-groups (16384)

// ---------------------------------------------------------------------------
// MEASUREMENT ROUND (R9): k1 is launched 3x (idempotent: rewrites identical
// partials; deterministic). dur_us - 39.6 = 2*(k1 + gap) separates
// "k1 at feed floor, k2+overhead dominates" from "k1 has hidden serial cost".
// Kernel bodies are byte-identical to R8.
// ---------------------------------------------------------------------------
__global__ __launch_bounds__(TPB, 2) void seg_hist_kernel(
    const float* __restrict__ pred, const int* __restrict__ labels,
    float* __restrict__ partial, int N) {
  const int b = blockIdx.y;
  const int ng = N >> 2;  // float4 groups per image (200704)
  __shared__ float sumh[TPB * MAXL];          // 16896 B
  __shared__ unsigned char cnth[TPB * CSTR];  // 4608 B
  __shared__ float xred[2][2][MAXL];          // 528 B
  const int tid = threadIdx.x;

  float* sh = &sumh[tid * MAXL];
  unsigned char* ch = &cnth[tid * CSTR];
#pragma unroll
  for (int i = 0; i < MAXL; ++i) sh[i] = 0.f;
#pragma unroll
  for (int i = 0; i < CSTR / 4; ++i) reinterpret_cast<unsigned*>(ch)[i] = 0u;

  const float4* p = reinterpret_cast<const float4*>(pred) + (size_t)b * 4 * ng;
  const int4* lb = reinterpret_cast<const int4*>(labels) + (size_t)b * ng;
  const int start = blockIdx.x * TPB + tid;
  // 13 slots for blocks 0..31 (start < 4096), else 12; uniform per block.
  const bool has13 = (start + 12 * GSTR) < ng;

  auto ld = [&](int g, float4& c0, float4& c1, float4& c2, float4& c3,
                int4& l) {
    c0 = p[g];
    c1 = p[g + ng];
    c2 = p[g + 2 * ng];
    c3 = p[g + 3 * ng];
    l = lb[g];
  };
  auto proc = [&](const float4& c0, const float4& c1, const float4& c2,
                  const float4& c3, const int4& l) {
    float s0 = c0.x * c0.x + c1.x * c1.x + c2.x * c2.x + c3.x * c3.x;
    float s1 = c0.y * c0.y + c1.y * c1.y + c2.y * c2.y + c3.y * c3.y;
    float s2 = c0.z * c0.z + c1.z * c1.z + c2.z * c2.z + c3.z * c3.z;
    float s3 = c0.w * c0.w + c1.w * c1.w + c2.w * c2.w + c3.w * c3.w;
    const bool e01 = l.x == l.y, e02 = l.x == l.z, e03 = l.x == l.w;
    const bool e12 = l.y == l.z, e13 = l.y == l.w, e23 = l.z == l.w;
    const float w1 = s1 + (e01 ? s0 : 0.f);
    const float w2 = s2 + (e12 ? s1 : 0.f) + (e02 ? s0 : 0.f);
    const float w3 =
        s3 + (e23 ? s2 : 0.f) + (e13 ? s1 : 0.f) + (e03 ? s0 : 0.f);
    const unsigned m1 = 1u + (unsigned)e01;
    const unsigned m2 = 1u + (unsigned)e12 + (unsigned)e02;
    const unsigned m3 = 1u + (unsigned)e23 + (unsigned)e13 + (unsigned)e03;
    const float r0 = sh[l.x], r1 = sh[l.y], r2 = sh[l.z], r3 = sh[l.w];
    const unsigned q0 = ch[l.x], q1 = ch[l.y], q2 = ch[l.z], q3 = ch[l.w];
    sh[l.x] = r0 + s0;
    sh[l.y] = r1 + w1;
    sh[l.z] = r2 + w2;
    sh[l.w] = r3 + w3;
    ch[l.x] = (unsigned char)(q0 + 1u);
    ch[l.y] = (unsigned char)(q1 + m1);
    ch[l.z] = (unsigned char)(q2 + m2);
    ch[l.w] = (unsigned char)(q3 + m3);
  };

  float4 A0, A1, A2, A3, B0, B1, B2, B3, C0, C1, C2, C3;
  int4 Al, Bl, Cl;

  // prologue: fill the 3-deep pipeline
  ld(start + 0 * GSTR, A0, A1, A2, A3, Al);
  ld(start + 1 * GSTR, B0, B1, B2, B3, Bl);
  ld(start + 2 * GSTR, C0, C1, C2, C3, Cl);

#pragma unroll
  for (int k = 0; k < 3; ++k) {
    proc(A0, A1, A2, A3, Al);
    ld(start + (3 * k + 3) * GSTR, A0, A1, A2, A3, Al);
    proc(B0, B1, B2, B3, Bl);
    ld(start + (3 * k + 4) * GSTR, B0, B1, B2, B3, Bl);
    proc(C0, C1, C2, C3, Cl);
    ld(start + (3 * k + 5) * GSTR, C0, C1, C2, C3, Cl);
  }
  // tail: slots 9..11 (+ predicated slot 12)
  proc(A0, A1, A2, A3, Al);
  if (has13) ld(start + 12 * GSTR, A0, A1, A2, A3, Al);
  proc(B0, B1, B2, B3, Bl);
  proc(C0, C1, C2, C3, Cl);
  if (has13) proc(A0, A1, A2, A3, Al);
  __syncthreads();

  const int wave = tid >> 6;
  const int lane = tid & 63;
  if (lane < MAXL) {  // wave w reduces thread-slices w*64 .. w*64+63
    float fs = 0.f;
    unsigned fc = 0u;
#pragma unroll 8
    for (int u = 0; u < 64; ++u) {
      fs += sumh[(wave * 64 + u) * MAXL + lane];
      fc += (unsigned)cnth[(wave * 64 + u) * CSTR + lane];
    }
    xred[wave][0][lane] = fs;
    xred[wave][1][lane] = (float)fc;
  }
  __syncthreads();
  if (tid < MAXL) {
    partial[(size_t)(b * 2 * MAXL + tid) * PB + blockIdx.x] =
        xred[0][0][tid] + xred[1][0][tid];
    partial[(size_t)(b * 2 * MAXL + MAXL + tid) * PB + blockIdx.x] =
        xred[0][1][tid] + xred[1][1][tid];
  }
}

// ---------------------------------------------------------------------------
// Kernel 2 (1 block, 512 threads): slot-per-thread row sums of the partials
// (independent float4 loads), then s = ssq/card^2, nk = max present label,
// pairwise log-loss.
// ---------------------------------------------------------------------------
__global__ __launch_bounds__(512) void reduce_finalize_kernel(
    const float* __restrict__ partial, float* __restrict__ out) {
  __shared__ float red[8 * 2 * MAXL];  // 528 slots
  __shared__ float s_val[8 * MAXL];
  __shared__ float s_flag[8 * MAXL];
  __shared__ float s_invden[8];
  __shared__ float s_part[8];
  const int tid = threadIdx.x;
  const int wave = tid >> 6;
  const int lane = tid & 63;

  {
    int slot = tid;
    const float4* row =
        reinterpret_cast<const float4*>(partial) + (size_t)slot * (PB / 4);
    float a0 = 0.f, a1 = 0.f;
#pragma unroll 8
    for (int u = 0; u < PB / 4; u += 2) {
      float4 x = row[u], y = row[u + 1];
      a0 += x.x + x.y + x.z + x.w;
      a1 += y.x + y.y + y.z + y.w;
    }
    if (slot < 8 * 2 * MAXL) red[slot] = a0 + a1;
  }
  if (tid < 8 * 2 * MAXL - 512) {
    int slot = 512 + tid;
    const float4* row =
        reinterpret_cast<const float4*>(partial) + (size_t)slot * (PB / 4);
    float a0 = 0.f, a1 = 0.f;
#pragma unroll 8
    for (int u = 0; u < PB / 4; u += 2) {
      float4 x = row[u], y = row[u + 1];
      a0 += x.x + x.y + x.z + x.w;
      a1 += y.x + y.y + y.z + y.w;
    }
    red[slot] = a0 + a1;
  }
  __syncthreads();

  for (int i = tid; i < 8 * MAXL; i += 512) {
    int b = i / MAXL, l = i - b * MAXL;
    float cnt = red[b * 2 * MAXL + MAXL + l];
    float ssq = red[b * 2 * MAXL + l];
    float safe = cnt > 0.f ? cnt : 1.f;
    s_val[i] = ssq / (safe * safe);
    s_flag[i] = (l >= 1 && cnt > 0.f) ? 1.f : 0.f;
  }
  __syncthreads();
  if (tid < 8) {
    int nk = 0;
    for (int l = MAXL - 1; l >= 0; --l) {
      if (red[tid * 2 * MAXL + MAXL + l] > 0.f) {
        nk = l;
        break;
      }
    }
    s_invden[tid] = (nk > 1) ? 1.f / ((float)nk * ((float)nk - 1.f)) : 0.f;
  }
  __syncthreads();

  float local = 0.f;
  const int total = 8 * MAXL * MAXL;
  for (int idx = tid; idx < total; idx += 512) {
    int b = idx / (MAXL * MAXL);
    int r = idx - b * MAXL * MAXL;
    int i = r / MAXL;
    int j = r - i * MAXL;
    if (i < j && s_flag[b * MAXL + i] != 0.f && s_flag[b * MAXL + j] != 0.f) {
      float S = s_val[b * MAXL + i] + s_val[b * MAXL + j];
      float d = 3.0f - sqrtf(S);
      local += logf(d * d + 1.f) * s_invden[b];
    }
  }
  for (int off = 32; off; off >>= 1) local += __shfl_down(local, off, 64);
  if (lane == 0) s_part[wave] = local;
  __syncthreads();
  if (tid == 0) {
    float tot = 0.f;
    for (int w = 0; w < 8; ++w) tot += s_part[w];
    out[0] = tot;
  }
}

extern "C" void kernel_launch(void* const* d_in, const int* in_sizes, int n_in,
                              void* d_out, int out_size, void* d_ws,
                              size_t ws_size, hipStream_t stream) {
  const float* pred = (const float*)d_in[0];
  // d_in[1] = kernels_mask: unused by the reference math -> never read.
  const int* labels = (const int*)d_in[2];
  float* out = (float*)d_out;

  const int B = 8;
  const int N = in_sizes[2] / B;  // 896*896 = 802816

  float* partial = (float*)d_ws;  // 528 slots x PB floats = 270 KB

  dim3 grid(PB, B);  // 1024 blocks of 128 threads, 4 blocks/CU
  // MEASUREMENT: 3x k1 (idempotent, deterministic). dur_us delta vs R8
  // gives 2*(k1+gap) to split k1 from k2+overhead.
  seg_hist_kernel<<<grid, dim3(TPB), 0, stream>>>(pred, labels, partial, N);
  seg_hist_kernel<<<grid, dim3(TPB), 0, stream>>>(pred, labels, partial, N);
  seg_hist_kernel<<<grid, dim3(TPB), 0, stream>>>(pred, labels, partial, N);
  reduce_finalize_kernel<<<dim3(1), dim3(512), 0, stream>>>(partial, out);
}

// Round 10
// 47.805 us; speedup vs baseline: 1.6864x; 1.6864x over previous
//
#include <hip/hip_runtime.h>

#define MAXL 33
#define CSTR 36  // u8 count-slice stride (9 dwords, dword-aligned per thread)
#define PB 256   // blocks per batch image  (R10: 128->256, real occupancy test)
#define TPB 128  // threads per block
#define GSTR (PB * TPB)  // grid stride in float4-groups (32768)

// ---------------------------------------------------------------------------
// Kernel 1: per-(batch,label) segmented sums, no atomics anywhere.
// Per-THREAD private LDS histograms: f32 sums (odd dword stride 33 ->
// conflict-free banks) and u8 counts (stride 36 B). Per 4-pixel slot:
// batch-read bins (one LDS round-trip), merge duplicate labels in registers
// via pairwise eq-masks (writes in pixel order; DS pipe in-order per wave ->
// last write wins), batch-write. Depth-3 static register pipeline.
// R10 single change: PB 128->256. R9's 3x-launch measurement put k1 at
// ~18-20 us (~7.1 TB/s from L3) with only 4 blocks/CU resident (grid-capped;
// R7's LDS shrink never raised occupancy because the grid was the cap).
// 2048 blocks -> 7 blocks/CU (LDS-capped) = 14 waves/CU: tests whether k1 is
// DS-chain-latency-bound (helps) or L3-BW/DS-throughput-bound (neutral).
// NOTE (R6 lesson): no ticket+__threadfence() fusion; 1024 device-scope
// fences cost ~110 us. The kernel boundary is the cheap fence.
// ---------------------------------------------------------------------------
__global__ __launch_bounds__(TPB, 2) void seg_hist_kernel(
    const float* __restrict__ pred, const int* __restrict__ labels,
    float* __restrict__ partial, int N) {
  const int b = blockIdx.y;
  const int ng = N >> 2;  // float4 groups per image (200704)
  __shared__ float sumh[TPB * MAXL];          // 16896 B
  __shared__ unsigned char cnth[TPB * CSTR];  // 4608 B
  __shared__ float xred[2][2][MAXL];          // 528 B
  const int tid = threadIdx.x;

  float* sh = &sumh[tid * MAXL];
  unsigned char* ch = &cnth[tid * CSTR];
#pragma unroll
  for (int i = 0; i < MAXL; ++i) sh[i] = 0.f;
#pragma unroll
  for (int i = 0; i < CSTR / 4; ++i) reinterpret_cast<unsigned*>(ch)[i] = 0u;

  const float4* p = reinterpret_cast<const float4*>(pred) + (size_t)b * 4 * ng;
  const int4* lb = reinterpret_cast<const int4*>(labels) + (size_t)b * ng;
  const int start = blockIdx.x * TPB + tid;
  // 200704 = 6*32768 + 4096: threads with start < 4096 (blocks 0..31 of each
  // row) do a 7th slot; uniform per block.
  const bool has7 = (start + 6 * GSTR) < ng;

  auto ld = [&](int g, float4& c0, float4& c1, float4& c2, float4& c3,
                int4& l) {
    c0 = p[g];
    c1 = p[g + ng];
    c2 = p[g + 2 * ng];
    c3 = p[g + 3 * ng];
    l = lb[g];
  };
  auto proc = [&](const float4& c0, const float4& c1, const float4& c2,
                  const float4& c3, const int4& l) {
    float s0 = c0.x * c0.x + c1.x * c1.x + c2.x * c2.x + c3.x * c3.x;
    float s1 = c0.y * c0.y + c1.y * c1.y + c2.y * c2.y + c3.y * c3.y;
    float s2 = c0.z * c0.z + c1.z * c1.z + c2.z * c2.z + c3.z * c3.z;
    float s3 = c0.w * c0.w + c1.w * c1.w + c2.w * c2.w + c3.w * c3.w;
    const bool e01 = l.x == l.y, e02 = l.x == l.z, e03 = l.x == l.w;
    const bool e12 = l.y == l.z, e13 = l.y == l.w, e23 = l.z == l.w;
    const float w1 = s1 + (e01 ? s0 : 0.f);
    const float w2 = s2 + (e12 ? s1 : 0.f) + (e02 ? s0 : 0.f);
    const float w3 =
        s3 + (e23 ? s2 : 0.f) + (e13 ? s1 : 0.f) + (e03 ? s0 : 0.f);
    const unsigned m1 = 1u + (unsigned)e01;
    const unsigned m2 = 1u + (unsigned)e12 + (unsigned)e02;
    const unsigned m3 = 1u + (unsigned)e23 + (unsigned)e13 + (unsigned)e03;
    const float r0 = sh[l.x], r1 = sh[l.y], r2 = sh[l.z], r3 = sh[l.w];
    const unsigned q0 = ch[l.x], q1 = ch[l.y], q2 = ch[l.z], q3 = ch[l.w];
    sh[l.x] = r0 + s0;
    sh[l.y] = r1 + w1;
    sh[l.z] = r2 + w2;
    sh[l.w] = r3 + w3;
    ch[l.x] = (unsigned char)(q0 + 1u);
    ch[l.y] = (unsigned char)(q1 + m1);
    ch[l.z] = (unsigned char)(q2 + m2);
    ch[l.w] = (unsigned char)(q3 + m3);
  };

  float4 A0, A1, A2, A3, B0, B1, B2, B3, C0, C1, C2, C3;
  int4 Al, Bl, Cl;

  // prologue: fill the 3-deep pipeline
  ld(start + 0 * GSTR, A0, A1, A2, A3, Al);
  ld(start + 1 * GSTR, B0, B1, B2, B3, Bl);
  ld(start + 2 * GSTR, C0, C1, C2, C3, Cl);

  proc(A0, A1, A2, A3, Al);
  ld(start + 3 * GSTR, A0, A1, A2, A3, Al);
  proc(B0, B1, B2, B3, Bl);
  ld(start + 4 * GSTR, B0, B1, B2, B3, Bl);
  proc(C0, C1, C2, C3, Cl);
  ld(start + 5 * GSTR, C0, C1, C2, C3, Cl);
  proc(A0, A1, A2, A3, Al);
  if (has7) ld(start + 6 * GSTR, A0, A1, A2, A3, Al);
  proc(B0, B1, B2, B3, Bl);
  proc(C0, C1, C2, C3, Cl);
  if (has7) proc(A0, A1, A2, A3, Al);
  __syncthreads();

  const int wave = tid >> 6;
  const int lane = tid & 63;
  if (lane < MAXL) {  // wave w reduces thread-slices w*64 .. w*64+63
    float fs = 0.f;
    unsigned fc = 0u;
#pragma unroll 8
    for (int u = 0; u < 64; ++u) {
      fs += sumh[(wave * 64 + u) * MAXL + lane];
      fc += (unsigned)cnth[(wave * 64 + u) * CSTR + lane];
    }
    xred[wave][0][lane] = fs;
    xred[wave][1][lane] = (float)fc;
  }
  __syncthreads();
  if (tid < MAXL) {
    partial[(size_t)(b * 2 * MAXL + tid) * PB + blockIdx.x] =
        xred[0][0][tid] + xred[1][0][tid];
    partial[(size_t)(b * 2 * MAXL + MAXL + tid) * PB + blockIdx.x] =
        xred[0][1][tid] + xred[1][1][tid];
  }
}

// ---------------------------------------------------------------------------
// Kernel 2 (1 block, 512 threads): slot-per-thread row sums of the partials
// (independent float4 loads), then s = ssq/card^2, nk = max present label,
// pairwise log-loss.
// ---------------------------------------------------------------------------
__global__ __launch_bounds__(512) void reduce_finalize_kernel(
    const float* __restrict__ partial, float* __restrict__ out) {
  __shared__ float red[8 * 2 * MAXL];  // 528 slots
  __shared__ float s_val[8 * MAXL];
  __shared__ float s_flag[8 * MAXL];
  __shared__ float s_invden[8];
  __shared__ float s_part[8];
  const int tid = threadIdx.x;
  const int wave = tid >> 6;
  const int lane = tid & 63;

  {
    int slot = tid;
    const float4* row =
        reinterpret_cast<const float4*>(partial) + (size_t)slot * (PB / 4);
    float a0 = 0.f, a1 = 0.f;
#pragma unroll 8
    for (int u = 0; u < PB / 4; u += 2) {
      float4 x = row[u], y = row[u + 1];
      a0 += x.x + x.y + x.z + x.w;
      a1 += y.x + y.y + y.z + y.w;
    }
    if (slot < 8 * 2 * MAXL) red[slot] = a0 + a1;
  }
  if (tid < 8 * 2 * MAXL - 512) {
    int slot = 512 + tid;
    const float4* row =
        reinterpret_cast<const float4*>(partial) + (size_t)slot * (PB / 4);
    float a0 = 0.f, a1 = 0.f;
#pragma unroll 8
    for (int u = 0; u < PB / 4; u += 2) {
      float4 x = row[u], y = row[u + 1];
      a0 += x.x + x.y + x.z + x.w;
      a1 += y.x + y.y + y.z + y.w;
    }
    red[slot] = a0 + a1;
  }
  __syncthreads();

  for (int i = tid; i < 8 * MAXL; i += 512) {
    int b = i / MAXL, l = i - b * MAXL;
    float cnt = red[b * 2 * MAXL + MAXL + l];
    float ssq = red[b * 2 * MAXL + l];
    float safe = cnt > 0.f ? cnt : 1.f;
    s_val[i] = ssq / (safe * safe);
    s_flag[i] = (l >= 1 && cnt > 0.f) ? 1.f : 0.f;
  }
  __syncthreads();
  if (tid < 8) {
    int nk = 0;
    for (int l = MAXL - 1; l >= 0; --l) {
      if (red[tid * 2 * MAXL + MAXL + l] > 0.f) {
        nk = l;
        break;
      }
    }
    s_invden[tid] = (nk > 1) ? 1.f / ((float)nk * ((float)nk - 1.f)) : 0.f;
  }
  __syncthreads();

  float local = 0.f;
  const int total = 8 * MAXL * MAXL;
  for (int idx = tid; idx < total; idx += 512) {
    int b = idx / (MAXL * MAXL);
    int r = idx - b * MAXL * MAXL;
    int i = r / MAXL;
    int j = r - i * MAXL;
    if (i < j && s_flag[b * MAXL + i] != 0.f && s_flag[b * MAXL + j] != 0.f) {
      float S = s_val[b * MAXL + i] + s_val[b * MAXL + j];
      float d = 3.0f - sqrtf(S);
      local += logf(d * d + 1.f) * s_invden[b];
    }
  }
  for (int off = 32; off; off >>= 1) local += __shfl_down(local, off, 64);
  if (lane == 0) s_part[wave] = local;
  __syncthreads();
  if (tid == 0) {
    float tot = 0.f;
    for (int w = 0; w < 8; ++w) tot += s_part[w];
    out[0] = tot;
  }
}

extern "C" void kernel_launch(void* const* d_in, const int* in_sizes, int n_in,
                              void* d_out, int out_size, void* d_ws,
                              size_t ws_size, hipStream_t stream) {
  const float* pred = (const float*)d_in[0];
  // d_in[1] = kernels_mask: unused by the reference math -> never read.
  const int* labels = (const int*)d_in[2];
  float* out = (float*)d_out;

  const int B = 8;
  const int N = in_sizes[2] / B;  // 896*896 = 802816

  float* partial = (float*)d_ws;  // 528 slots x PB floats = 540 KB

  dim3 grid(PB, B);  // 2048 blocks of 128 threads -> 7 blocks/CU (LDS-capped)
  seg_hist_kernel<<<grid, dim3(TPB), 0, stream>>>(pred, labels, partial, N);
  reduce_finalize_kernel<<<dim3(1), dim3(512), 0, stream>>>(partial, out);
}

// Round 11
// 41.518 us; speedup vs baseline: 1.9418x; 1.1514x over previous
//
#include <hip/hip_runtime.h>

#define MAXL 33
#define NSLOT 66  // 33 ssq + 33 cnt per (b, block)
#define PB 128    // blocks per batch image
#define TPB 128   // threads per block
#define GSTR (PB * TPB)  // grid stride in float4-groups (16384)

// ---------------------------------------------------------------------------
// Kernel 1: per-(batch,label) segmented sums, no atomics.
// R11 layout changes (R10 lesson: k1 is at the ~7.1 TB/s L3 roofline; the
// remaining fat was k2's uncoalesced read + k1's flush):
//  * LDS hist TRANSPOSED to [bin][thread]: every main-loop DS access hits
//    bank tid%32 -> exact 2-way (free) REGARDLESS of label values; flush
//    reads hist[bin][lane] coalesced + wave shuffle-reduce.
//  * partial TRANSPOSED to [b][blk][66]: k1 writes 66 contiguous floats
//    (1 coalesced store), k2 reads lane-consecutive (256 B/wave-inst).
// Main loop unchanged: depth-3 static register pipeline, batch LDS
// read->merge-in-reg->write (in-order DS pipe: last write wins).
// NOTE (R6): no ticket+__threadfence fusion (~110 us of L2 maintenance).
// ---------------------------------------------------------------------------
__global__ __launch_bounds__(TPB, 2) void seg_hist_kernel(
    const float* __restrict__ pred, const int* __restrict__ labels,
    float* __restrict__ partial, int N) {
  const int b = blockIdx.y;
  const int ng = N >> 2;  // float4 groups per image (200704)
  __shared__ float sumh[MAXL][TPB];     // 16896 B, [bin][thread]
  __shared__ unsigned cnth[MAXL][TPB];  // 16896 B
  __shared__ float xr[NSLOT];
  const int tid = threadIdx.x;

  // Each thread clears its OWN column (flat index i == tid mod TPB) -> no
  // barrier needed before the main loop.
  {
    float* sf = &sumh[0][0];
    unsigned* cf = &cnth[0][0];
    for (int i = tid; i < MAXL * TPB; i += TPB) {
      sf[i] = 0.f;
      cf[i] = 0u;
    }
  }

  const float4* p = reinterpret_cast<const float4*>(pred) + (size_t)b * 4 * ng;
  const int4* lb = reinterpret_cast<const int4*>(labels) + (size_t)b * ng;
  const int start = blockIdx.x * TPB + tid;
  // 200704 = 12*16384 + 4096: threads with start < 4096 do a 13th slot.
  const bool has13 = (start + 12 * GSTR) < ng;

  auto ld = [&](int g, float4& c0, float4& c1, float4& c2, float4& c3,
                int4& l) {
    c0 = p[g];
    c1 = p[g + ng];
    c2 = p[g + 2 * ng];
    c3 = p[g + 3 * ng];
    l = lb[g];
  };
  auto proc = [&](const float4& c0, const float4& c1, const float4& c2,
                  const float4& c3, const int4& l) {
    float s0 = c0.x * c0.x + c1.x * c1.x + c2.x * c2.x + c3.x * c3.x;
    float s1 = c0.y * c0.y + c1.y * c1.y + c2.y * c2.y + c3.y * c3.y;
    float s2 = c0.z * c0.z + c1.z * c1.z + c2.z * c2.z + c3.z * c3.z;
    float s3 = c0.w * c0.w + c1.w * c1.w + c2.w * c2.w + c3.w * c3.w;
    const bool e01 = l.x == l.y, e02 = l.x == l.z, e03 = l.x == l.w;
    const bool e12 = l.y == l.z, e13 = l.y == l.w, e23 = l.z == l.w;
    const float w1 = s1 + (e01 ? s0 : 0.f);
    const float w2 = s2 + (e12 ? s1 : 0.f) + (e02 ? s0 : 0.f);
    const float w3 =
        s3 + (e23 ? s2 : 0.f) + (e13 ? s1 : 0.f) + (e03 ? s0 : 0.f);
    const unsigned m1 = 1u + (unsigned)e01;
    const unsigned m2 = 1u + (unsigned)e12 + (unsigned)e02;
    const unsigned m3 = 1u + (unsigned)e23 + (unsigned)e13 + (unsigned)e03;
    const float r0 = sumh[l.x][tid], r1 = sumh[l.y][tid];
    const float r2 = sumh[l.z][tid], r3 = sumh[l.w][tid];
    const unsigned q0 = cnth[l.x][tid], q1 = cnth[l.y][tid];
    const unsigned q2 = cnth[l.z][tid], q3 = cnth[l.w][tid];
    sumh[l.x][tid] = r0 + s0;
    sumh[l.y][tid] = r1 + w1;
    sumh[l.z][tid] = r2 + w2;
    sumh[l.w][tid] = r3 + w3;
    cnth[l.x][tid] = q0 + 1u;
    cnth[l.y][tid] = q1 + m1;
    cnth[l.z][tid] = q2 + m2;
    cnth[l.w][tid] = q3 + m3;
  };

  float4 A0, A1, A2, A3, B0, B1, B2, B3, C0, C1, C2, C3;
  int4 Al, Bl, Cl;

  ld(start + 0 * GSTR, A0, A1, A2, A3, Al);
  ld(start + 1 * GSTR, B0, B1, B2, B3, Bl);
  ld(start + 2 * GSTR, C0, C1, C2, C3, Cl);

#pragma unroll
  for (int k = 0; k < 3; ++k) {
    proc(A0, A1, A2, A3, Al);
    ld(start + (3 * k + 3) * GSTR, A0, A1, A2, A3, Al);
    proc(B0, B1, B2, B3, Bl);
    ld(start + (3 * k + 4) * GSTR, B0, B1, B2, B3, Bl);
    proc(C0, C1, C2, C3, Cl);
    ld(start + (3 * k + 5) * GSTR, C0, C1, C2, C3, Cl);
  }
  proc(A0, A1, A2, A3, Al);
  if (has13) ld(start + 12 * GSTR, A0, A1, A2, A3, Al);
  proc(B0, B1, B2, B3, Bl);
  proc(C0, C1, C2, C3, Cl);
  if (has13) proc(A0, A1, A2, A3, Al);
  __syncthreads();

  // Flush: wave w handles bins w, w+2, ...; coalesced [bin][lane] reads +
  // 6-step shuffle reduce; lane 0 stages to xr; one coalesced global store.
  const int wave = tid >> 6;
  const int lane = tid & 63;
  for (int bin = wave; bin < MAXL; bin += 2) {
    float fs = sumh[bin][lane] + sumh[bin][64 + lane];
    unsigned fc = cnth[bin][lane] + cnth[bin][64 + lane];
    for (int off = 32; off; off >>= 1) {
      fs += __shfl_down(fs, off, 64);
      fc += __shfl_down(fc, off, 64);
    }
    if (lane == 0) {
      xr[bin] = fs;
      xr[MAXL + bin] = (float)fc;
    }
  }
  __syncthreads();
  if (tid < NSLOT)
    partial[(size_t)(b * PB + blockIdx.x) * NSLOT + tid] = xr[tid];
}

// ---------------------------------------------------------------------------
// Kernel 2 (1 block, 576 threads; 528 active in the reduce): slot s=b*66+j
// sums partial[(b*PB+blk)*66+j] over blk — lane-consecutive addresses ->
// fully coalesced 256 B/wave-inst, 128 independent loads/thread. Then
// s=ssq/card^2, nk=max present label, pairwise log-loss.
// ---------------------------------------------------------------------------
__global__ __launch_bounds__(576) void reduce_finalize_kernel(
    const float* __restrict__ partial, float* __restrict__ out) {
  __shared__ float red[8 * NSLOT];  // [b][66]: j<33 ssq, j>=33 cnt
  __shared__ float s_invden[8];
  __shared__ float s_part[9];
  const int tid = threadIdx.x;
  const int wave = tid >> 6;
  const int lane = tid & 63;

  if (tid < 8 * NSLOT) {
    const int bb = tid / NSLOT, s = tid - bb * NSLOT;
    const float* base = partial + (size_t)bb * PB * NSLOT + s;
    float a0 = 0.f, a1 = 0.f, a2 = 0.f, a3 = 0.f;
#pragma unroll 8
    for (int blk = 0; blk < PB; blk += 4) {
      a0 += base[(size_t)(blk + 0) * NSLOT];
      a1 += base[(size_t)(blk + 1) * NSLOT];
      a2 += base[(size_t)(blk + 2) * NSLOT];
      a3 += base[(size_t)(blk + 3) * NSLOT];
    }
    red[tid] = (a0 + a1) + (a2 + a3);
  }
  __syncthreads();

  if (tid < 8) {
    int nk = 0;
    for (int l = MAXL - 1; l >= 1; --l) {
      if (red[tid * NSLOT + MAXL + l] > 0.f) {
        nk = l;
        break;
      }
    }
    s_invden[tid] = (nk > 1) ? 1.f / ((float)nk * ((float)nk - 1.f)) : 0.f;
  }
  __syncthreads();

  float local = 0.f;
  const int total = 8 * MAXL * MAXL;
  for (int idx = tid; idx < total; idx += 576) {
    int bb = idx / (MAXL * MAXL);
    int r = idx - bb * (MAXL * MAXL);
    int i = r / MAXL;
    int j = r - i * MAXL;
    if (i >= 1 && i < j) {
      float ci = red[bb * NSLOT + MAXL + i];
      float cj = red[bb * NSLOT + MAXL + j];
      if (ci > 0.f && cj > 0.f) {
        float si = red[bb * NSLOT + i] / (ci * ci);
        float sj = red[bb * NSLOT + j] / (cj * cj);
        float d = 3.0f - sqrtf(si + sj);
        local += logf(d * d + 1.f) * s_invden[bb];
      }
    }
  }
  for (int off = 32; off; off >>= 1) local += __shfl_down(local, off, 64);
  if (lane == 0) s_part[wave] = local;
  __syncthreads();
  if (tid == 0) {
    float tot = 0.f;
    for (int w = 0; w < 9; ++w) tot += s_part[w];
    out[0] = tot;
  }
}

extern "C" void kernel_launch(void* const* d_in, const int* in_sizes, int n_in,
                              void* d_out, int out_size, void* d_ws,
                              size_t ws_size, hipStream_t stream) {
  const float* pred = (const float*)d_in[0];
  // d_in[1] = kernels_mask: unused by the reference math -> never read.
  const int* labels = (const int*)d_in[2];
  float* out = (float*)d_out;

  const int B = 8;
  const int N = in_sizes[2] / B;  // 896*896 = 802816

  float* partial = (float*)d_ws;  // [8][PB][66] floats = 270 KB

  dim3 grid(PB, B);  // 1024 blocks of 128 threads
  seg_hist_kernel<<<grid, dim3(TPB), 0, stream>>>(pred, labels, partial, N);
  reduce_finalize_kernel<<<dim3(1), dim3(576), 0, stream>>>(partial, out);
}

// Round 12
// 39.658 us; speedup vs baseline: 2.0329x; 1.0469x over previous
//
#include <hip/hip_runtime.h>

#define MAXL 33
#define PB 128   // blocks per batch image
#define TPB 128  // threads per block

// ---------------------------------------------------------------------------
// FINAL (R12 = R5 verbatim, the best-measured variant: 39.2 us).
// Budget (uncontaminated dur_us differentials, R8/R9): k1 ~18.5 us at the
// ~7.0 TB/s L3-feed roofline (128.5 MB single-pass, validated against the
// harness's own fill kernels at 7.0-7.2 TB/s); in-graph gap ~2 us; k2 ~2.5 us;
// fixed per-replay graph overhead ~15.5 us (untouchable from kernel code).
// Exhausted levers: global atomics -> none (R1->R2), LDS atomics -> none
// (R3->R5: CAS-loop f32 atomicAdd was the 80 us wall, per-thread private
// histograms removed it), occupancy x1.75 (R10: regression), VMEM pipeline
// depth x3 (R8: null), LDS bank transpose + coalesced k2 (R11: null),
// single-dispatch fusion via ticket+__threadfence (R6: -77 us, 1024
// device-scope fences do serialized L2 maintenance).
//
// Kernel 1: per-(batch,label) segmented sums, no atomics anywhere.
// Per-THREAD private LDS histograms, f32 sums + u32 counts, odd dword
// stride 33 -> uniform over all 32 banks. Per 4-pixel iteration: batch-read
// the 4 bins (one LDS round-trip), merge duplicate labels in registers via
// pairwise eq-masks (writes issued in pixel order; DS pipe is in-order per
// wave -> last write wins under collisions), batch-write. Global loads
// register double-buffered one iteration ahead.
// ---------------------------------------------------------------------------
__global__ __launch_bounds__(TPB, 2) void seg_hist_kernel(
    const float* __restrict__ pred, const int* __restrict__ labels,
    float* __restrict__ partial, int N) {
  const int b = blockIdx.y;
  const int ng = N >> 2;  // float4 groups per image
  __shared__ float sumh[TPB * MAXL];     // 16.9 KB
  __shared__ unsigned cnth[TPB * MAXL];  // 16.9 KB
  __shared__ float xred[2][2][MAXL];
  const int tid = threadIdx.x;

  float* sh = &sumh[tid * MAXL];
  unsigned* ch = &cnth[tid * MAXL];
#pragma unroll
  for (int i = 0; i < MAXL; ++i) {
    sh[i] = 0.f;
    ch[i] = 0u;
  }

  const float4* p = reinterpret_cast<const float4*>(pred) + (size_t)b * 4 * ng;
  const int4* lb = reinterpret_cast<const int4*>(labels) + (size_t)b * ng;
  const int STRIDE = PB * TPB;

  int g = blockIdx.x * TPB + tid;  // always < ng on first iter
  float4 c0 = p[g], c1 = p[g + ng], c2 = p[g + 2 * ng], c3 = p[g + 3 * ng];
  int4 l = lb[g];

  while (true) {
    const int gn = g + STRIDE;
    const bool more = gn < ng;
    float4 n0, n1, n2, n3;
    int4 nl;
    if (more) {  // prefetch next iteration
      n0 = p[gn];
      n1 = p[gn + ng];
      n2 = p[gn + 2 * ng];
      n3 = p[gn + 3 * ng];
      nl = lb[gn];
    }

    // per-pixel sum over channels
    float s0 = c0.x * c0.x + c1.x * c1.x + c2.x * c2.x + c3.x * c3.x;
    float s1 = c0.y * c0.y + c1.y * c1.y + c2.y * c2.y + c3.y * c3.y;
    float s2 = c0.z * c0.z + c1.z * c1.z + c2.z * c2.z + c3.z * c3.z;
    float s3 = c0.w * c0.w + c1.w * c1.w + c2.w * c2.w + c3.w * c3.w;

    // duplicate-label merge masks
    const bool e01 = l.x == l.y, e02 = l.x == l.z, e03 = l.x == l.w;
    const bool e12 = l.y == l.z, e13 = l.y == l.w, e23 = l.z == l.w;
    const float w1 = s1 + (e01 ? s0 : 0.f);
    const float w2 = s2 + (e12 ? s1 : 0.f) + (e02 ? s0 : 0.f);
    const float w3 =
        s3 + (e23 ? s2 : 0.f) + (e13 ? s1 : 0.f) + (e03 ? s0 : 0.f);
    const unsigned m1 = 1u + (unsigned)e01;
    const unsigned m2 = 1u + (unsigned)e12 + (unsigned)e02;
    const unsigned m3 = 1u + (unsigned)e23 + (unsigned)e13 + (unsigned)e03;

    // batched reads (one LDS round-trip), then ordered writes (last wins)
    const float r0 = sh[l.x], r1 = sh[l.y], r2 = sh[l.z], r3 = sh[l.w];
    const unsigned q0 = ch[l.x], q1 = ch[l.y], q2 = ch[l.z], q3 = ch[l.w];
    sh[l.x] = r0 + s0;
    sh[l.y] = r1 + w1;
    sh[l.z] = r2 + w2;
    sh[l.w] = r3 + w3;
    ch[l.x] = q0 + 1u;
    ch[l.y] = q1 + m1;
    ch[l.z] = q2 + m2;
    ch[l.w] = q3 + m3;

    if (!more) break;
    c0 = n0;
    c1 = n1;
    c2 = n2;
    c3 = n3;
    l = nl;
    g = gn;
  }
  __syncthreads();

  const int wave = tid >> 6;
  const int lane = tid & 63;
  if (lane < MAXL) {  // wave w reduces thread-slices w*64 .. w*64+63
    float fs = 0.f;
    unsigned fc = 0u;
#pragma unroll 8
    for (int u = 0; u < 64; ++u) {
      fs += sumh[(wave * 64 + u) * MAXL + lane];
      fc += cnth[(wave * 64 + u) * MAXL + lane];
    }
    xred[wave][0][lane] = fs;
    xred[wave][1][lane] = (float)fc;
  }
  __syncthreads();
  if (tid < MAXL) {
    partial[(size_t)(b * 2 * MAXL + tid) * PB + blockIdx.x] =
        xred[0][0][tid] + xred[1][0][tid];
    partial[(size_t)(b * 2 * MAXL + MAXL + tid) * PB + blockIdx.x] =
        xred[0][1][tid] + xred[1][1][tid];
  }
}

// ---------------------------------------------------------------------------
// Kernel 2 (1 block, 512 threads): slot-per-thread row sums of the partials
// (no shuffle chains, independent float4 loads), then s = ssq/card^2,
// nk = max present label, pairwise log-loss.
// ---------------------------------------------------------------------------
__global__ __launch_bounds__(512) void reduce_finalize_kernel(
    const float* __restrict__ partial, float* __restrict__ out) {
  __shared__ float red[8 * 2 * MAXL];  // 528 slots
  __shared__ float s_val[8 * MAXL];
  __shared__ float s_flag[8 * MAXL];
  __shared__ float s_invden[8];
  __shared__ float s_part[8];
  const int tid = threadIdx.x;
  const int wave = tid >> 6;
  const int lane = tid & 63;

  {
    int slot = tid;
    const float4* row =
        reinterpret_cast<const float4*>(partial) + (size_t)slot * (PB / 4);
    float a0 = 0.f, a1 = 0.f;
#pragma unroll 8
    for (int u = 0; u < PB / 4; u += 2) {
      float4 x = row[u], y = row[u + 1];
      a0 += x.x + x.y + x.z + x.w;
      a1 += y.x + y.y + y.z + y.w;
    }
    if (slot < 8 * 2 * MAXL) red[slot] = a0 + a1;
  }
  if (tid < 8 * 2 * MAXL - 512) {
    int slot = 512 + tid;
    const float4* row =
        reinterpret_cast<const float4*>(partial) + (size_t)slot * (PB / 4);
    float a0 = 0.f, a1 = 0.f;
#pragma unroll 8
    for (int u = 0; u < PB / 4; u += 2) {
      float4 x = row[u], y = row[u + 1];
      a0 += x.x + x.y + x.z + x.w;
      a1 += y.x + y.y + y.z + y.w;
    }
    red[slot] = a0 + a1;
  }
  __syncthreads();

  for (int i = tid; i < 8 * MAXL; i += 512) {
    int b = i / MAXL, l = i - b * MAXL;
    float cnt = red[b * 2 * MAXL + MAXL + l];
    float ssq = red[b * 2 * MAXL + l];
    float safe = cnt > 0.f ? cnt : 1.f;
    s_val[i] = ssq / (safe * safe);
    s_flag[i] = (l >= 1 && cnt > 0.f) ? 1.f : 0.f;
  }
  __syncthreads();
  if (tid < 8) {
    int nk = 0;
    for (int l = MAXL - 1; l >= 0; --l) {
      if (red[tid * 2 * MAXL + MAXL + l] > 0.f) {
        nk = l;
        break;
      }
    }
    s_invden[tid] = (nk > 1) ? 1.f / ((float)nk * ((float)nk - 1.f)) : 0.f;
  }
  __syncthreads();

  float local = 0.f;
  const int total = 8 * MAXL * MAXL;
  for (int idx = tid; idx < total; idx += 512) {
    int b = idx / (MAXL * MAXL);
    int r = idx - b * MAXL * MAXL;
    int i = r / MAXL;
    int j = r - i * MAXL;
    if (i < j && s_flag[b * MAXL + i] != 0.f && s_flag[b * MAXL + j] != 0.f) {
      float S = s_val[b * MAXL + i] + s_val[b * MAXL + j];
      float d = 3.0f - sqrtf(S);
      local += logf(d * d + 1.f) * s_invden[b];
    }
  }
  for (int off = 32; off; off >>= 1) local += __shfl_down(local, off, 64);
  if (lane == 0) s_part[wave] = local;
  __syncthreads();
  if (tid == 0) {
    float tot = 0.f;
    for (int w = 0; w < 8; ++w) tot += s_part[w];
    out[0] = tot;
  }
}

extern "C" void kernel_launch(void* const* d_in, const int* in_sizes, int n_in,
                              void* d_out, int out_size, void* d_ws,
                              size_t ws_size, hipStream_t stream) {
  const float* pred = (const float*)d_in[0];
  // d_in[1] = kernels_mask: unused by the reference math -> never read.
  const int* labels = (const int*)d_in[2];
  float* out = (float*)d_out;

  const int B = 8;
  const int N = in_sizes[2] / B;  // 896*896 = 802816

  float* partial = (float*)d_ws;  // 528 slots x PB floats = 270 KB

  dim3 grid(PB, B);  // 1024 blocks of 128 threads, 4 blocks/CU
  seg_hist_kernel<<<grid, dim3(TPB), 0, stream>>>(pred, labels, partial, N);
  reduce_finalize_kernel<<<dim3(1), dim3(512), 0, stream>>>(partial, out);
}